// Round 9
// baseline (16804.669 us; speedup 1.0000x reference)
//
#include <hip/hip_runtime.h>
#include <hip/hip_cooperative_groups.h>

namespace cg = cooperative_groups;

#define NNODES 50000
#define NEDGES 800000
#define HDIM 128
#define CDIM 10
#define LNUM 3
#define ONUM 2
#define KHOPS 10
#define GNUM 128
#define EPSBN 1e-5f

typedef unsigned int uint;
typedef unsigned short ushort;
typedef __attribute__((ext_vector_type(8))) short bf16x8;
typedef __attribute__((ext_vector_type(4))) float f32x4;

__device__ __forceinline__ ushort f2bf(float f) {
    uint u = __builtin_bit_cast(uint, f);
    uint r = (u + 0x7fffu + ((u >> 16) & 1u)) >> 16;
    return (ushort)r;
}
__device__ __forceinline__ float bf2f_lo(uint u) { return __builtin_bit_cast(float, u << 16); }
__device__ __forceinline__ float bf2f_hi(uint u) { return __builtin_bit_cast(float, u & 0xffff0000u); }

// ---------------- MFMA GEMM (z-projection) ----------------
// out = A @ Wt^T + bias (Wt bf16 [n][k]); writes bf16 z and hid = f2bf(fw0[0]*v).
// A f32 when a_bf16==0 else bf16. grid.y==1 -> "_b" parameter set (A shared).
#define KC 128
#define LDA 136
__global__ __launch_bounds__(256) void mfma_gemm(
    const void* __restrict__ A0, int a_bf16,
    const ushort* __restrict__ Wt,
    const float* __restrict__ bias, const float* __restrict__ fw0,
    ushort* __restrict__ outz, ushort* __restrict__ hidz,
    const ushort* __restrict__ Wt_b, const float* __restrict__ bias_b,
    const float* __restrict__ fw0_b, ushort* __restrict__ outz_b,
    ushort* __restrict__ hidz_b)
{
    if (blockIdx.y) { Wt = Wt_b; bias = bias_b; fw0 = fw0_b; outz = outz_b; hidz = hidz_b; }
    __shared__ ushort sA[64 * LDA];
    __shared__ ushort sB[128 * LDA];
    const int row0 = blockIdx.x * 64;
    const int tid  = threadIdx.x;
    const int w    = tid >> 6;
    const int lane = tid & 63;
    const int lr   = lane & 15;
    const int q    = lane >> 4;

    f32x4 acc[8];
#pragma unroll
    for (int nt = 0; nt < 8; ++nt)
#pragma unroll
        for (int j = 0; j < 4; ++j) acc[nt][j] = 0.f;

    for (int idx = tid; idx < 64 * 64; idx += 256) {
        int r = idx >> 6, kp = idx & 63;
        int row = row0 + r;
        uint pv = 0;
        if (row < NNODES) {
            if (a_bf16) {
                pv = ((const uint*)((const ushort*)A0 + (size_t)row * HDIM))[kp];
            } else {
                float2 v = ((const float2*)((const float*)A0 + (size_t)row * HDIM))[kp];
                pv = (uint)f2bf(v.x) | ((uint)f2bf(v.y) << 16);
            }
        }
        ((uint*)(sA + r * LDA))[kp] = pv;
    }
    for (int idx = tid; idx < 128 * 64; idx += 256) {
        int n = idx >> 6, kp = idx & 63;
        ((uint*)(sB + n * LDA))[kp] = ((const uint*)(Wt + (size_t)n * HDIM))[kp];
    }
    __syncthreads();
#pragma unroll
    for (int kt = 0; kt < 4; ++kt) {
        bf16x8 a = *(const bf16x8*)(sA + (16 * w + lr) * LDA + kt * 32 + q * 8);
#pragma unroll
        for (int nt = 0; nt < 8; ++nt) {
            bf16x8 b = *(const bf16x8*)(sB + (nt * 16 + lr) * LDA + kt * 32 + q * 8);
            acc[nt] = __builtin_amdgcn_mfma_f32_16x16x32_bf16(a, b, acc[nt], 0, 0, 0);
        }
    }

    const float f0 = fw0[0];
#pragma unroll
    for (int nt = 0; nt < 8; ++nt) {
        int col = nt * 16 + lr;
        float bs = bias[col];
#pragma unroll
        for (int r = 0; r < 4; ++r) {
            int row = row0 + 16 * w + q * 4 + r;
            if (row >= NNODES) continue;
            float v = acc[nt][r] + bs;
            size_t off = (size_t)row * HDIM + col;
            outz[off] = f2bf(v);
            hidz[off] = f2bf(f0 * v);
        }
    }
}

// ---------------- fused epilogue: h = relu(bn2( relu(bn1([A0|A1]@Wfold+bfold)) @ Wn2 + bn2 )) ----------------
// Stage 1: K=256 over Wt1 [n=128][k=256]; xc round-trips through LDS (bf16, row-major).
// Stage 2: K=128 over Wt2 [128][128]. In-place safe vs A0 (reads staged before writes).
__global__ __launch_bounds__(256) void mfma_gemm2(
    const ushort* __restrict__ A0, const ushort* __restrict__ A1,
    const ushort* __restrict__ Wt1, const float* __restrict__ b1v,
    const float* __restrict__ g1v, const float* __restrict__ be1v,
    const ushort* __restrict__ Wt2, const float* __restrict__ b2v,
    const float* __restrict__ g2v, const float* __restrict__ be2v,
    ushort* __restrict__ outh)
{
    __shared__ ushort sA[64 * LDA];
    __shared__ ushort sB[128 * LDA];
    const int row0 = blockIdx.x * 64;
    const int tid  = threadIdx.x;
    const int w    = tid >> 6;
    const int lane = tid & 63;
    const int lr   = lane & 15;
    const int q    = lane >> 4;

    f32x4 acc[8];
#pragma unroll
    for (int nt = 0; nt < 8; ++nt)
#pragma unroll
        for (int j = 0; j < 4; ++j) acc[nt][j] = 0.f;

    for (int c = 0; c < 2; ++c) {
        const ushort* Asrc = c ? A1 : A0;
        for (int idx = tid; idx < 64 * 64; idx += 256) {
            int r = idx >> 6, kp = idx & 63;
            int row = row0 + r;
            uint pv = 0;
            if (row < NNODES) pv = ((const uint*)(Asrc + (size_t)row * HDIM))[kp];
            ((uint*)(sA + r * LDA))[kp] = pv;
        }
        for (int idx = tid; idx < 128 * 64; idx += 256) {
            int n = idx >> 6, kp = idx & 63;
            ((uint*)(sB + n * LDA))[kp] = ((const uint*)(Wt1 + (size_t)n * 2 * HDIM + c * KC))[kp];
        }
        __syncthreads();
#pragma unroll
        for (int kt = 0; kt < 4; ++kt) {
            bf16x8 a = *(const bf16x8*)(sA + (16 * w + lr) * LDA + kt * 32 + q * 8);
#pragma unroll
            for (int nt = 0; nt < 8; ++nt) {
                bf16x8 b = *(const bf16x8*)(sB + (nt * 16 + lr) * LDA + kt * 32 + q * 8);
                acc[nt] = __builtin_amdgcn_mfma_f32_16x16x32_bf16(a, b, acc[nt], 0, 0, 0);
            }
        }
        __syncthreads();
    }

    // epilogue 1 -> xc (bf16) into sA, row-major tile
#pragma unroll
    for (int nt = 0; nt < 8; ++nt) {
        int col = nt * 16 + lr;
        float bs = b1v[col];
        float sc = g1v[col] * rsqrtf(1.f + EPSBN);
        float bt = be1v[col];
#pragma unroll
        for (int r = 0; r < 4; ++r) {
            int lrow = 16 * w + q * 4 + r;
            float v = (acc[nt][r] + bs) * sc + bt;
            v = fmaxf(v, 0.f);
            sA[lrow * LDA + col] = f2bf(v);
        }
    }
    // stage Wn2
    for (int idx = tid; idx < 128 * 64; idx += 256) {
        int n = idx >> 6, kp = idx & 63;
        ((uint*)(sB + n * LDA))[kp] = ((const uint*)(Wt2 + (size_t)n * HDIM))[kp];
    }
    __syncthreads();

    f32x4 acc2[8];
#pragma unroll
    for (int nt = 0; nt < 8; ++nt)
#pragma unroll
        for (int j = 0; j < 4; ++j) acc2[nt][j] = 0.f;
#pragma unroll
    for (int kt = 0; kt < 4; ++kt) {
        bf16x8 a = *(const bf16x8*)(sA + (16 * w + lr) * LDA + kt * 32 + q * 8);
#pragma unroll
        for (int nt = 0; nt < 8; ++nt) {
            bf16x8 b = *(const bf16x8*)(sB + (nt * 16 + lr) * LDA + kt * 32 + q * 8);
            acc2[nt] = __builtin_amdgcn_mfma_f32_16x16x32_bf16(a, b, acc2[nt], 0, 0, 0);
        }
    }
#pragma unroll
    for (int nt = 0; nt < 8; ++nt) {
        int col = nt * 16 + lr;
        float bs = b2v[col];
        float sc = g2v[col] * rsqrtf(1.f + EPSBN);
        float bt = be2v[col];
#pragma unroll
        for (int r = 0; r < 4; ++r) {
            int row = row0 + 16 * w + q * 4 + r;
            if (row >= NNODES) continue;
            float v = (acc2[nt][r] + bs) * sc + bt;
            v = fmaxf(v, 0.f);
            outh[(size_t)row * HDIM + col] = f2bf(v);
        }
    }
}

// weight transposes: blocks 0-5 W_in, 6-8 Wn2 (Kd=128)
__global__ void wtrans_all(const float* __restrict__ W_in, const float* __restrict__ Wn2,
                           ushort* __restrict__ Wt_in, ushort* __restrict__ Wt_n2)
{
    int b = blockIdx.x;
    const float* W; ushort* Wt;
    if (b < 6) { W = W_in + (size_t)b * HDIM * HDIM;       Wt = Wt_in + (size_t)b * HDIM * HDIM; }
    else       { W = Wn2 + (size_t)(b - 6) * HDIM * HDIM;  Wt = Wt_n2 + (size_t)(b - 6) * HDIM * HDIM; }
    for (int idx = threadIdx.x; idx < HDIM * HDIM; idx += 512) {
        int k = idx >> 7, n = idx & 127;
        Wt[(size_t)n * HDIM + k] = f2bf(W[idx]);
    }
}

// fold W_out@Wn1 -> Wt_fold bf16 [l][n][k] (k=0..255), b_fold = b_out@Wn1 + bn1
__global__ void wfold(const float* __restrict__ W_out, const float* __restrict__ b_out,
                      const float* __restrict__ Wn1, const float* __restrict__ bn1,
                      ushort* __restrict__ Wt_fold, float* __restrict__ b_fold)
{
    const int l = blockIdx.y, bx = blockIdx.x;          // bx: 0..63
    const float* Wo = W_out + (size_t)l * 2 * HDIM * HDIM;
    const float* Wn = Wn1   + (size_t)l * HDIM * HDIM;
    const int n = threadIdx.x & 127;
    const int j = threadIdx.x >> 7;                     // 0..1
#pragma unroll
    for (int t = 0; t < 2; ++t) {
        int kk = bx * 4 + j * 2 + t;
        float s = 0.f;
        for (int m = 0; m < HDIM; ++m) s += Wo[(size_t)kk * HDIM + m] * Wn[(size_t)m * HDIM + n];
        Wt_fold[(size_t)l * HDIM * 2 * HDIM + (size_t)n * 2 * HDIM + kk] = f2bf(s);
    }
    if (bx == 0 && j == 0) {
        float s = bn1[(size_t)l * HDIM + n];
        for (int m = 0; m < HDIM; ++m) s += b_out[(size_t)l * HDIM + m] * Wn[(size_t)m * HDIM + n];
        b_fold[(size_t)l * HDIM + n] = s;
    }
}

// small f32 GEMM for the [G,H] tail
__global__ void gemm_rows(const float* __restrict__ A0,
                          const float* __restrict__ W, const float* __restrict__ bias,
                          float* __restrict__ out, int N, int Hout, int relu)
{
    __shared__ float a[8][HDIM];
    const int row0 = blockIdx.x * 8;
    const int tid  = threadIdx.x;
    for (int r = 0; r < 8; ++r) {
        int row = row0 + r;
        a[r][tid] = (row < N) ? A0[(size_t)row * HDIM + tid] : 0.f;
    }
    __syncthreads();
    if (tid < Hout) {
        float acc[8];
#pragma unroll
        for (int r = 0; r < 8; ++r) acc[r] = 0.f;
        for (int k = 0; k < HDIM; ++k) {
            float wv = W[(size_t)k * Hout + tid];
#pragma unroll
            for (int r = 0; r < 8; ++r) acc[r] += a[r][k] * wv;
        }
        const float bs = bias[tid];
        for (int r = 0; r < 8; ++r) {
            int row = row0 + r;
            if (row >= N) break;
            float v = acc[r] + bs;
            if (relu) v = fmaxf(v, 0.f);
            out[(size_t)row * Hout + tid] = v;
        }
    }
}

// ---------- bucketed CSR build: 64 slots/node, 4 B entries (w_bf16<<16 | src) ----------
__global__ void fill2(const int* __restrict__ ei, const float* __restrict__ ew,
                      int* __restrict__ cnt0, int* __restrict__ cnt1,
                      uint* __restrict__ bk0, uint* __restrict__ bk1)
{
    int e = blockIdx.x * blockDim.x + threadIdx.x;
    if (e >= NEDGES) return;
    int o = blockIdx.y;
    const int* dst = ei + (size_t)o * 2 * NEDGES;
    const int* src = dst + NEDGES;
    float w = ew[(size_t)o * NEDGES + e];
    int d = dst[e];
    int pos = atomicAdd((o ? cnt1 : cnt0) + d, 1);
    if (pos < 64)
        (o ? bk1 : bk0)[((size_t)d << 6) + pos] = ((uint)f2bf(w) << 16) | (uint)src[e];
}

// ---------- cooperative multi-hop gather SpMM (all K hops, both orders) ----------
// Persistent waves; one 64-lane wave handles a fixed strided set of node-orders.
// Hop parity picks z ping/pong. Even hops: hid += fw[k-1]*z_{k-1}[node] + fw[k]*z_k.
// grid.sync() + device fence between hops (cross-XCD z visibility).
__global__ __launch_bounds__(256) void spmm_multi(
    const int* __restrict__ cnt0, const uint* __restrict__ bk0,
    const int* __restrict__ cnt1, const uint* __restrict__ bk1,
    ushort* __restrict__ z0A, ushort* __restrict__ z0B,
    ushort* __restrict__ z1A, ushort* __restrict__ z1B,
    ushort* __restrict__ hid0, ushort* __restrict__ hid1,
    const float* __restrict__ fw0, const float* __restrict__ fw1)
{
    cg::grid_group grid = cg::this_grid();
    const int lane = threadIdx.x & 63;
    const int wid  = blockIdx.x * (blockDim.x >> 6) + (threadIdx.x >> 6);
    const int nw   = gridDim.x * (blockDim.x >> 6);

    for (int k = 1; k <= KHOPS; ++k) {
        const int do_hid = ((k & 1) == 0);
        const int wz = (k < KHOPS);
        for (int t = wid; t < 2 * NNODES; t += nw) {
            const int o    = (t >= NNODES);
            const int node = o ? t - NNODES : t;
            const int*  cnt = o ? cnt1 : cnt0;
            const uint* bk  = o ? bk1 : bk0;
            const uint* zi  = (const uint*)(o ? ((k & 1) ? z1A : z1B) : ((k & 1) ? z0A : z0B));
            uint*       zo  = (uint*)(o ? ((k & 1) ? z1B : z1A) : ((k & 1) ? z0B : z0A));
            uint*       hid = (uint*)(o ? hid1 : hid0);
            const float* fwp = (o ? fw1 : fw0) + (k - 1);

            int n = __builtin_amdgcn_readfirstlane(cnt[node]); n = n > 64 ? 64 : n;
            const uint* b = bk + ((size_t)node << 6);
            float ax = 0.f, ay = 0.f;
            int j = 0;
            for (; j + 3 < n; j += 4) {
                uint4 e4 = *(const uint4*)(b + j);
                uint u0 = zi[(size_t)(e4.x & 0xffffu) * 64 + lane];
                uint u1 = zi[(size_t)(e4.y & 0xffffu) * 64 + lane];
                uint u2 = zi[(size_t)(e4.z & 0xffffu) * 64 + lane];
                uint u3 = zi[(size_t)(e4.w & 0xffffu) * 64 + lane];
                float w0 = bf2f_hi(e4.x), w1 = bf2f_hi(e4.y);
                float w2 = bf2f_hi(e4.z), w3 = bf2f_hi(e4.w);
                ax += w0 * bf2f_lo(u0) + w1 * bf2f_lo(u1) + w2 * bf2f_lo(u2) + w3 * bf2f_lo(u3);
                ay += w0 * bf2f_hi(u0) + w1 * bf2f_hi(u1) + w2 * bf2f_hi(u2) + w3 * bf2f_hi(u3);
            }
            for (; j < n; ++j) {
                uint e = b[j];
                uint u = zi[(size_t)(e & 0xffffu) * 64 + lane];
                float wt = bf2f_hi(e);
                ax += wt * bf2f_lo(u);
                ay += wt * bf2f_hi(u);
            }
            if (wz)
                zo[(size_t)node * 64 + lane] = (uint)f2bf(ax) | ((uint)f2bf(ay) << 16);
            if (do_hid) {
                uint up = zi[(size_t)node * 64 + lane];
                uint hh = hid[(size_t)node * 64 + lane];
                const float c0 = fwp[0], c1 = fwp[1];
                float hx = bf2f_lo(hh) + c0 * bf2f_lo(up) + c1 * ax;
                float hy = bf2f_hi(hh) + c0 * bf2f_hi(up) + c1 * ay;
                hid[(size_t)node * 64 + lane] = (uint)f2bf(hx) | ((uint)f2bf(hy) << 16);
            }
        }
        __threadfence();   // device-scope: z must cross XCD L2s before next hop
        grid.sync();
    }
}

// ---------- segmented pool (batch sorted), bf16 input, no atomics ----------
__global__ __launch_bounds__(1024) void pool_seg(const ushort* __restrict__ h,
                                                 const int* __restrict__ batch,
                                                 float* __restrict__ pool)
{
    __shared__ float red[1024];
    const int gph = blockIdx.x;
    const int t  = threadIdx.x & 127;
    const int rr = threadIdx.x >> 7;
    int lo = 0, hi = NNODES;
    while (lo < hi) { int m = (lo + hi) >> 1; if (batch[m] < gph) lo = m + 1; else hi = m; }
    const int beg = lo;
    hi = NNODES;
    while (lo < hi) { int m = (lo + hi) >> 1; if (batch[m] < gph + 1) lo = m + 1; else hi = m; }
    const int end = lo;
    float acc = 0.f;
    for (int i = beg + rr; i < end; i += 8)
        acc += __builtin_bit_cast(float, (uint)h[(size_t)i * HDIM + t] << 16);
    red[threadIdx.x] = acc;
    __syncthreads();
    if (rr == 0) {
        float s = 0.f;
#pragma unroll
        for (int k = 0; k < 8; ++k) s += red[t + 128 * k];
        pool[(size_t)gph * HDIM + t] = s;
    }
}

extern "C" void kernel_launch(void* const* d_in, const int* in_sizes, int n_in,
                              void* d_out, int out_size, void* d_ws, size_t ws_size,
                              hipStream_t stream)
{
    const float* x     = (const float*)d_in[0];
    const int*   ei    = (const int*)  d_in[1];
    const float* ew    = (const float*)d_in[2];
    const int*   batch = (const int*)  d_in[3];
    const float* W_in  = (const float*)d_in[4];
    const float* b_in  = (const float*)d_in[5];
    const float* fW    = (const float*)d_in[6];
    const float* W_out = (const float*)d_in[7];
    const float* b_out = (const float*)d_in[8];
    const float* Wn1   = (const float*)d_in[9];
    const float* bn1   = (const float*)d_in[10];
    const float* g1    = (const float*)d_in[11];
    const float* be1   = (const float*)d_in[12];
    const float* Wn2   = (const float*)d_in[13];
    const float* bn2   = (const float*)d_in[14];
    const float* g2    = (const float*)d_in[15];
    const float* be2   = (const float*)d_in[16];
    const float* W1    = (const float*)d_in[17];
    const float* b1    = (const float*)d_in[18];
    const float* W2    = (const float*)d_in[19];
    const float* b2    = (const float*)d_in[20];
    float* out = (float*)d_out;

    const size_t NH = (size_t)NNODES * HDIM;
    ushort* wsu = (ushort*)d_ws;
    ushort* nb[3] = { wsu, wsu + NH, wsu + 2 * NH };      // node buffers bf16
    ushort* z0A = wsu + 3 * NH;
    ushort* z0B = z0A + NH;
    ushort* z1A = z0B + NH;
    ushort* z1B = z1A + NH;
    float*  f_pl  = (float*)(z1B + NH);
    float*  f_pl2 = f_pl + (size_t)GNUM * HDIM;
    float*  b_fold = f_pl2 + (size_t)GNUM * HDIM;          // 3*128 f32

    ushort* Wt_in   = (ushort*)(b_fold + 3 * HDIM);        // 6*128*128
    ushort* Wt_n2   = Wt_in + (size_t)6 * HDIM * HDIM;     // 3*128*128
    ushort* Wt_fold = Wt_n2 + (size_t)3 * HDIM * HDIM;     // 3*128*256

    int*  cnt0 = (int*)(Wt_fold + (size_t)3 * HDIM * 2 * HDIM);
    int*  cnt1 = cnt0 + NNODES;
    uint* bk0  = (uint*)(cnt1 + NNODES);
    uint* bk1  = bk0 + ((size_t)NNODES << 6);

    const int gemm_grid = (NNODES + 63) / 64;
    const int edge_grid = (NEDGES + 255) / 256;

    // cooperative grid size: guaranteed co-resident
    int occ = 0;
    if (hipOccupancyMaxActiveBlocksPerMultiprocessor(&occ, spmm_multi, 256, 0) != hipSuccess || occ < 1)
        occ = 2;
    if (occ > 8) occ = 8;
    const int coop_blocks = occ * 256;   // 256 CUs on MI355X

    wtrans_all<<<9, 512, 0, stream>>>(W_in, Wn2, Wt_in, Wt_n2);
    wfold<<<dim3(64, 3), 256, 0, stream>>>(W_out, b_out, Wn1, bn1, Wt_fold, b_fold);
    hipMemsetAsync(cnt0, 0, 2 * NNODES * sizeof(int), stream);
    fill2<<<dim3(edge_grid, 2), 256, 0, stream>>>(ei, ew, cnt0, cnt1, bk0, bk1);

    int ci = -1;   // -1: cur = x (f32)
    for (int l = 0; l < LNUM; ++l) {
        const int t0 = (l == 0) ? 0 : (ci + 1) % 3;
        const int t1 = (l == 0) ? 1 : (ci + 2) % 3;
        const void* curp = (l == 0) ? (const void*)x : (const void*)nb[ci];
        const int a_bf = (l == 0) ? 0 : 1;
        const int lo0 = l * ONUM, lo1 = lo0 + 1;

        // z_o = cur @ W_in[lo] + b_in -> bf16 z ; hid_o = fW[0]*z_o (bf16). Both orders.
        mfma_gemm<<<dim3(gemm_grid, 2), 256, 0, stream>>>(
            curp, a_bf, Wt_in + (size_t)lo0 * HDIM * HDIM,
            b_in + (size_t)lo0 * HDIM, fW + (size_t)lo0 * (KHOPS + 1), z0A, nb[t0],
            Wt_in + (size_t)lo1 * HDIM * HDIM, b_in + (size_t)lo1 * HDIM,
            fW + (size_t)lo1 * (KHOPS + 1), z1A, nb[t1]);

        // all K hops, both orders, one cooperative kernel
        {
            const int* a_cnt0 = cnt0; const uint* a_bk0 = bk0;
            const int* a_cnt1 = cnt1; const uint* a_bk1 = bk1;
            ushort *a_z0A = z0A, *a_z0B = z0B, *a_z1A = z1A, *a_z1B = z1B;
            ushort *a_h0 = nb[t0], *a_h1 = nb[t1];
            const float* a_fw0 = fW + (size_t)lo0 * (KHOPS + 1);
            const float* a_fw1 = fW + (size_t)lo1 * (KHOPS + 1);
            void* args[] = { &a_cnt0, &a_bk0, &a_cnt1, &a_bk1,
                             &a_z0A, &a_z0B, &a_z1A, &a_z1B,
                             &a_h0, &a_h1, &a_fw0, &a_fw1 };
            hipLaunchCooperativeKernel((const void*)spmm_multi,
                                       dim3(coop_blocks), dim3(256), args, 0, stream);
        }

        // h = relu(bn2( relu(bn1([hid0|hid1]@Wfold+bfold)) @ Wn2 + bn2 )) -> nb[t0]
        mfma_gemm2<<<gemm_grid, 256, 0, stream>>>(
            nb[t0], nb[t1],
            Wt_fold + (size_t)l * HDIM * 2 * HDIM, b_fold + (size_t)l * HDIM,
            g1 + (size_t)l * HDIM, be1 + (size_t)l * HDIM,
            Wt_n2 + (size_t)l * HDIM * HDIM, bn2 + (size_t)l * HDIM,
            g2 + (size_t)l * HDIM, be2 + (size_t)l * HDIM,
            nb[t0]);
        ci = t0;
    }

    pool_seg<<<GNUM, 1024, 0, stream>>>(nb[ci], batch, f_pl);
    gemm_rows<<<(GNUM + 7) / 8, 128, 0, stream>>>(f_pl,  W1, b1, f_pl2, GNUM, HDIM, 1);
    gemm_rows<<<(GNUM + 7) / 8, 128, 0, stream>>>(f_pl2, W2, b2, out,   GNUM, CDIM, 0);
}

// Round 10
// 2606.758 us; speedup vs baseline: 6.4466x; 6.4466x over previous
//
#include <hip/hip_runtime.h>

#define NNODES 50000
#define NEDGES 800000
#define HDIM 128
#define CDIM 10
#define LNUM 3
#define ONUM 2
#define KHOPS 10
#define GNUM 128
#define EPSBN 1e-5f

typedef unsigned int uint;
typedef unsigned short ushort;
typedef __attribute__((ext_vector_type(8))) short bf16x8;
typedef __attribute__((ext_vector_type(4))) float f32x4;

__device__ __forceinline__ ushort f2bf(float f) {
    uint u = __builtin_bit_cast(uint, f);
    uint r = (u + 0x7fffu + ((u >> 16) & 1u)) >> 16;
    return (ushort)r;
}
__device__ __forceinline__ float bf2f_lo(uint u) { return __builtin_bit_cast(float, u << 16); }
__device__ __forceinline__ float bf2f_hi(uint u) { return __builtin_bit_cast(float, u & 0xffff0000u); }

// ---------------- MFMA GEMM (z-projection) ----------------
// out = A @ Wt^T + bias (Wt bf16 [n][k]); writes bf16 z and hid = f2bf(fw0[0]*v).
// A f32 when a_bf16==0 else bf16. grid.y==1 -> "_b" parameter set (A shared).
#define KC 128
#define LDA 136
__global__ __launch_bounds__(256) void mfma_gemm(
    const void* __restrict__ A0, int a_bf16,
    const ushort* __restrict__ Wt,
    const float* __restrict__ bias, const float* __restrict__ fw0,
    ushort* __restrict__ outz, ushort* __restrict__ hidz,
    const ushort* __restrict__ Wt_b, const float* __restrict__ bias_b,
    const float* __restrict__ fw0_b, ushort* __restrict__ outz_b,
    ushort* __restrict__ hidz_b)
{
    if (blockIdx.y) { Wt = Wt_b; bias = bias_b; fw0 = fw0_b; outz = outz_b; hidz = hidz_b; }
    __shared__ ushort sA[64 * LDA];
    __shared__ ushort sB[128 * LDA];
    const int row0 = blockIdx.x * 64;
    const int tid  = threadIdx.x;
    const int w    = tid >> 6;
    const int lane = tid & 63;
    const int lr   = lane & 15;
    const int q    = lane >> 4;

    f32x4 acc[8];
#pragma unroll
    for (int nt = 0; nt < 8; ++nt)
#pragma unroll
        for (int j = 0; j < 4; ++j) acc[nt][j] = 0.f;

    for (int idx = tid; idx < 64 * 64; idx += 256) {
        int r = idx >> 6, kp = idx & 63;
        int row = row0 + r;
        uint pv = 0;
        if (row < NNODES) {
            if (a_bf16) {
                pv = ((const uint*)((const ushort*)A0 + (size_t)row * HDIM))[kp];
            } else {
                float2 v = ((const float2*)((const float*)A0 + (size_t)row * HDIM))[kp];
                pv = (uint)f2bf(v.x) | ((uint)f2bf(v.y) << 16);
            }
        }
        ((uint*)(sA + r * LDA))[kp] = pv;
    }
    for (int idx = tid; idx < 128 * 64; idx += 256) {
        int n = idx >> 6, kp = idx & 63;
        ((uint*)(sB + n * LDA))[kp] = ((const uint*)(Wt + (size_t)n * HDIM))[kp];
    }
    __syncthreads();
#pragma unroll
    for (int kt = 0; kt < 4; ++kt) {
        bf16x8 a = *(const bf16x8*)(sA + (16 * w + lr) * LDA + kt * 32 + q * 8);
#pragma unroll
        for (int nt = 0; nt < 8; ++nt) {
            bf16x8 b = *(const bf16x8*)(sB + (nt * 16 + lr) * LDA + kt * 32 + q * 8);
            acc[nt] = __builtin_amdgcn_mfma_f32_16x16x32_bf16(a, b, acc[nt], 0, 0, 0);
        }
    }

    const float f0 = fw0[0];
#pragma unroll
    for (int nt = 0; nt < 8; ++nt) {
        int col = nt * 16 + lr;
        float bs = bias[col];
#pragma unroll
        for (int r = 0; r < 4; ++r) {
            int row = row0 + 16 * w + q * 4 + r;
            if (row >= NNODES) continue;
            float v = acc[nt][r] + bs;
            size_t off = (size_t)row * HDIM + col;
            outz[off] = f2bf(v);
            hidz[off] = f2bf(f0 * v);
        }
    }
}

// ---------------- fused epilogue: h = relu(bn2( relu(bn1([A0|A1]@Wfold+bfold)) @ Wn2 + bn2 )) ----------------
// Stage 1: K=256 over Wt1 [n=128][k=256]; xc round-trips through LDS (bf16, row-major).
// Stage 2: K=128 over Wt2 [128][128]. In-place safe vs A0 (block reads only its own rows).
__global__ __launch_bounds__(256) void mfma_gemm2(
    const ushort* __restrict__ A0, const ushort* __restrict__ A1,
    const ushort* __restrict__ Wt1, const float* __restrict__ b1v,
    const float* __restrict__ g1v, const float* __restrict__ be1v,
    const ushort* __restrict__ Wt2, const float* __restrict__ b2v,
    const float* __restrict__ g2v, const float* __restrict__ be2v,
    ushort* __restrict__ outh)
{
    __shared__ ushort sA[64 * LDA];
    __shared__ ushort sB[128 * LDA];
    const int row0 = blockIdx.x * 64;
    const int tid  = threadIdx.x;
    const int w    = tid >> 6;
    const int lane = tid & 63;
    const int lr   = lane & 15;
    const int q    = lane >> 4;

    f32x4 acc[8];
#pragma unroll
    for (int nt = 0; nt < 8; ++nt)
#pragma unroll
        for (int j = 0; j < 4; ++j) acc[nt][j] = 0.f;

    for (int c = 0; c < 2; ++c) {
        const ushort* Asrc = c ? A1 : A0;
        for (int idx = tid; idx < 64 * 64; idx += 256) {
            int r = idx >> 6, kp = idx & 63;
            int row = row0 + r;
            uint pv = 0;
            if (row < NNODES) pv = ((const uint*)(Asrc + (size_t)row * HDIM))[kp];
            ((uint*)(sA + r * LDA))[kp] = pv;
        }
        for (int idx = tid; idx < 128 * 64; idx += 256) {
            int n = idx >> 6, kp = idx & 63;
            ((uint*)(sB + n * LDA))[kp] = ((const uint*)(Wt1 + (size_t)n * 2 * HDIM + c * KC))[kp];
        }
        __syncthreads();
#pragma unroll
        for (int kt = 0; kt < 4; ++kt) {
            bf16x8 a = *(const bf16x8*)(sA + (16 * w + lr) * LDA + kt * 32 + q * 8);
#pragma unroll
            for (int nt = 0; nt < 8; ++nt) {
                bf16x8 b = *(const bf16x8*)(sB + (nt * 16 + lr) * LDA + kt * 32 + q * 8);
                acc[nt] = __builtin_amdgcn_mfma_f32_16x16x32_bf16(a, b, acc[nt], 0, 0, 0);
            }
        }
        __syncthreads();
    }

    // epilogue 1 -> xc (bf16) into sA, row-major tile
#pragma unroll
    for (int nt = 0; nt < 8; ++nt) {
        int col = nt * 16 + lr;
        float bs = b1v[col];
        float sc = g1v[col] * rsqrtf(1.f + EPSBN);
        float bt = be1v[col];
#pragma unroll
        for (int r = 0; r < 4; ++r) {
            int lrow = 16 * w + q * 4 + r;
            float v = (acc[nt][r] + bs) * sc + bt;
            v = fmaxf(v, 0.f);
            sA[lrow * LDA + col] = f2bf(v);
        }
    }
    // stage Wn2
    for (int idx = tid; idx < 128 * 64; idx += 256) {
        int n = idx >> 6, kp = idx & 63;
        ((uint*)(sB + n * LDA))[kp] = ((const uint*)(Wt2 + (size_t)n * HDIM))[kp];
    }
    __syncthreads();

    f32x4 acc2[8];
#pragma unroll
    for (int nt = 0; nt < 8; ++nt)
#pragma unroll
        for (int j = 0; j < 4; ++j) acc2[nt][j] = 0.f;
#pragma unroll
    for (int kt = 0; kt < 4; ++kt) {
        bf16x8 a = *(const bf16x8*)(sA + (16 * w + lr) * LDA + kt * 32 + q * 8);
#pragma unroll
        for (int nt = 0; nt < 8; ++nt) {
            bf16x8 b = *(const bf16x8*)(sB + (nt * 16 + lr) * LDA + kt * 32 + q * 8);
            acc2[nt] = __builtin_amdgcn_mfma_f32_16x16x32_bf16(a, b, acc2[nt], 0, 0, 0);
        }
    }
#pragma unroll
    for (int nt = 0; nt < 8; ++nt) {
        int col = nt * 16 + lr;
        float bs = b2v[col];
        float sc = g2v[col] * rsqrtf(1.f + EPSBN);
        float bt = be2v[col];
#pragma unroll
        for (int r = 0; r < 4; ++r) {
            int row = row0 + 16 * w + q * 4 + r;
            if (row >= NNODES) continue;
            float v = (acc2[nt][r] + bs) * sc + bt;
            v = fmaxf(v, 0.f);
            outh[(size_t)row * HDIM + col] = f2bf(v);
        }
    }
}

// weight transposes: blocks 0-5 W_in, 6-8 Wn2 (Kd=128)
__global__ void wtrans_all(const float* __restrict__ W_in, const float* __restrict__ Wn2,
                           ushort* __restrict__ Wt_in, ushort* __restrict__ Wt_n2)
{
    int b = blockIdx.x;
    const float* W; ushort* Wt;
    if (b < 6) { W = W_in + (size_t)b * HDIM * HDIM;       Wt = Wt_in + (size_t)b * HDIM * HDIM; }
    else       { W = Wn2 + (size_t)(b - 6) * HDIM * HDIM;  Wt = Wt_n2 + (size_t)(b - 6) * HDIM * HDIM; }
    for (int idx = threadIdx.x; idx < HDIM * HDIM; idx += 512) {
        int k = idx >> 7, n = idx & 127;
        Wt[(size_t)n * HDIM + k] = f2bf(W[idx]);
    }
}

// fold W_out@Wn1 -> Wt_fold bf16 [l][n][k] (k=0..255), b_fold = b_out@Wn1 + bn1
__global__ void wfold(const float* __restrict__ W_out, const float* __restrict__ b_out,
                      const float* __restrict__ Wn1, const float* __restrict__ bn1,
                      ushort* __restrict__ Wt_fold, float* __restrict__ b_fold)
{
    const int l = blockIdx.y, bx = blockIdx.x;          // bx: 0..63
    const float* Wo = W_out + (size_t)l * 2 * HDIM * HDIM;
    const float* Wn = Wn1   + (size_t)l * HDIM * HDIM;
    const int n = threadIdx.x & 127;
    const int j = threadIdx.x >> 7;                     // 0..1
#pragma unroll
    for (int t = 0; t < 2; ++t) {
        int kk = bx * 4 + j * 2 + t;
        float s = 0.f;
        for (int m = 0; m < HDIM; ++m) s += Wo[(size_t)kk * HDIM + m] * Wn[(size_t)m * HDIM + n];
        Wt_fold[(size_t)l * HDIM * 2 * HDIM + (size_t)n * 2 * HDIM + kk] = f2bf(s);
    }
    if (bx == 0 && j == 0) {
        float s = bn1[(size_t)l * HDIM + n];
        for (int m = 0; m < HDIM; ++m) s += b_out[(size_t)l * HDIM + m] * Wn[(size_t)m * HDIM + n];
        b_fold[(size_t)l * HDIM + n] = s;
    }
}

// small f32 GEMM for the [G,H] tail
__global__ void gemm_rows(const float* __restrict__ A0,
                          const float* __restrict__ W, const float* __restrict__ bias,
                          float* __restrict__ out, int N, int Hout, int relu)
{
    __shared__ float a[8][HDIM];
    const int row0 = blockIdx.x * 8;
    const int tid  = threadIdx.x;
    for (int r = 0; r < 8; ++r) {
        int row = row0 + r;
        a[r][tid] = (row < N) ? A0[(size_t)row * HDIM + tid] : 0.f;
    }
    __syncthreads();
    if (tid < Hout) {
        float acc[8];
#pragma unroll
        for (int r = 0; r < 8; ++r) acc[r] = 0.f;
        for (int k = 0; k < HDIM; ++k) {
            float wv = W[(size_t)k * Hout + tid];
#pragma unroll
            for (int r = 0; r < 8; ++r) acc[r] += a[r][k] * wv;
        }
        const float bs = bias[tid];
        for (int r = 0; r < 8; ++r) {
            int row = row0 + r;
            if (row >= N) break;
            float v = acc[r] + bs;
            if (relu) v = fmaxf(v, 0.f);
            out[(size_t)row * Hout + tid] = v;
        }
    }
}

// ---------- bucketed CSR build: 64 slots/node, 4 B entries (w_bf16<<16 | src) ----------
__global__ void fill2(const int* __restrict__ ei, const float* __restrict__ ew,
                      int* __restrict__ cnt0, int* __restrict__ cnt1,
                      uint* __restrict__ bk0, uint* __restrict__ bk1)
{
    int e = blockIdx.x * blockDim.x + threadIdx.x;
    if (e >= NEDGES) return;
    int o = blockIdx.y;
    const int* dst = ei + (size_t)o * 2 * NEDGES;
    const int* src = dst + NEDGES;
    float w = ew[(size_t)o * NEDGES + e];
    int d = dst[e];
    int pos = atomicAdd((o ? cnt1 : cnt0) + d, 1);
    if (pos < 64)
        (o ? bk1 : bk0)[((size_t)d << 6) + pos] = ((uint)f2bf(w) << 16) | (uint)src[e];
}

// ---------- full-row gather SpMM, both orders (grid.y=2) ----------
// One 64-lane wave per node; lane owns 2 cols (uint). Even hops (do_hid):
// hid(bf16) += fwp[0]*zin[node] + fwp[1]*znew. write_z=0 skips dead final z store.
__global__ void spmm2(const int* __restrict__ cnt0, const uint* __restrict__ bk0,
                      const int* __restrict__ cnt1, const uint* __restrict__ bk1,
                      const ushort* __restrict__ zin0, ushort* __restrict__ zout0,
                      const ushort* __restrict__ zin1, ushort* __restrict__ zout1,
                      ushort* __restrict__ hid0, ushort* __restrict__ hid1,
                      const float* __restrict__ fw0p, const float* __restrict__ fw1p,
                      int do_hid, int write_z)
{
    const int node = blockIdx.x * 4 + (threadIdx.x >> 6);
    if (node >= NNODES) return;
    const int o    = blockIdx.y;
    const int lane = threadIdx.x & 63;
    const int*  cnt = o ? cnt1 : cnt0;
    const uint* bk  = o ? bk1 : bk0;
    const uint* zi  = (const uint*)(o ? zin1 : zin0);
    uint*       zo  = (uint*)(o ? zout1 : zout0);
    uint*       hid = (uint*)(o ? hid1 : hid0);
    const float* fwp = o ? fw1p : fw0p;

    int n = __builtin_amdgcn_readfirstlane(cnt[node]); n = n > 64 ? 64 : n;
    const uint* b = bk + ((size_t)node << 6);
    float ax = 0.f, ay = 0.f;
    int j = 0;
    for (; j + 3 < n; j += 4) {
        uint4 e4 = *(const uint4*)(b + j);           // wave-uniform 16 B broadcast
        uint u0 = zi[(size_t)(e4.x & 0xffffu) * 64 + lane];
        uint u1 = zi[(size_t)(e4.y & 0xffffu) * 64 + lane];
        uint u2 = zi[(size_t)(e4.z & 0xffffu) * 64 + lane];
        uint u3 = zi[(size_t)(e4.w & 0xffffu) * 64 + lane];
        float w0 = bf2f_hi(e4.x), w1 = bf2f_hi(e4.y);
        float w2 = bf2f_hi(e4.z), w3 = bf2f_hi(e4.w);
        ax += w0 * bf2f_lo(u0) + w1 * bf2f_lo(u1) + w2 * bf2f_lo(u2) + w3 * bf2f_lo(u3);
        ay += w0 * bf2f_hi(u0) + w1 * bf2f_hi(u1) + w2 * bf2f_hi(u2) + w3 * bf2f_hi(u3);
    }
    for (; j < n; ++j) {
        uint e = b[j];
        uint u = zi[(size_t)(e & 0xffffu) * 64 + lane];
        float wt = bf2f_hi(e);
        ax += wt * bf2f_lo(u);
        ay += wt * bf2f_hi(u);
    }
    if (write_z)
        zo[(size_t)node * 64 + lane] = (uint)f2bf(ax) | ((uint)f2bf(ay) << 16);
    if (do_hid) {
        uint up = zi[(size_t)node * 64 + lane];
        uint hh = hid[(size_t)node * 64 + lane];
        const float c0 = fwp[0], c1 = fwp[1];
        float hx = bf2f_lo(hh) + c0 * bf2f_lo(up) + c1 * ax;
        float hy = bf2f_hi(hh) + c0 * bf2f_hi(up) + c1 * ay;
        hid[(size_t)node * 64 + lane] = (uint)f2bf(hx) | ((uint)f2bf(hy) << 16);
    }
}

// ---------- segmented pool (batch sorted), bf16 input, no atomics ----------
__global__ __launch_bounds__(1024) void pool_seg(const ushort* __restrict__ h,
                                                 const int* __restrict__ batch,
                                                 float* __restrict__ pool)
{
    __shared__ float red[1024];
    const int gph = blockIdx.x;
    const int t  = threadIdx.x & 127;
    const int rr = threadIdx.x >> 7;
    int lo = 0, hi = NNODES;
    while (lo < hi) { int m = (lo + hi) >> 1; if (batch[m] < gph) lo = m + 1; else hi = m; }
    const int beg = lo;
    hi = NNODES;
    while (lo < hi) { int m = (lo + hi) >> 1; if (batch[m] < gph + 1) lo = m + 1; else hi = m; }
    const int end = lo;
    float acc = 0.f;
    for (int i = beg + rr; i < end; i += 8)
        acc += __builtin_bit_cast(float, (uint)h[(size_t)i * HDIM + t] << 16);
    red[threadIdx.x] = acc;
    __syncthreads();
    if (rr == 0) {
        float s = 0.f;
#pragma unroll
        for (int k = 0; k < 8; ++k) s += red[t + 128 * k];
        pool[(size_t)gph * HDIM + t] = s;
    }
}

extern "C" void kernel_launch(void* const* d_in, const int* in_sizes, int n_in,
                              void* d_out, int out_size, void* d_ws, size_t ws_size,
                              hipStream_t stream)
{
    const float* x     = (const float*)d_in[0];
    const int*   ei    = (const int*)  d_in[1];
    const float* ew    = (const float*)d_in[2];
    const int*   batch = (const int*)  d_in[3];
    const float* W_in  = (const float*)d_in[4];
    const float* b_in  = (const float*)d_in[5];
    const float* fW    = (const float*)d_in[6];
    const float* W_out = (const float*)d_in[7];
    const float* b_out = (const float*)d_in[8];
    const float* Wn1   = (const float*)d_in[9];
    const float* bn1   = (const float*)d_in[10];
    const float* g1    = (const float*)d_in[11];
    const float* be1   = (const float*)d_in[12];
    const float* Wn2   = (const float*)d_in[13];
    const float* bn2   = (const float*)d_in[14];
    const float* g2    = (const float*)d_in[15];
    const float* be2   = (const float*)d_in[16];
    const float* W1    = (const float*)d_in[17];
    const float* b1    = (const float*)d_in[18];
    const float* W2    = (const float*)d_in[19];
    const float* b2    = (const float*)d_in[20];
    float* out = (float*)d_out;

    const size_t NH = (size_t)NNODES * HDIM;
    ushort* wsu = (ushort*)d_ws;
    ushort* nb[3] = { wsu, wsu + NH, wsu + 2 * NH };      // node buffers bf16
    ushort* z0A = wsu + 3 * NH;
    ushort* z0B = z0A + NH;
    ushort* z1A = z0B + NH;
    ushort* z1B = z1A + NH;
    float*  f_pl  = (float*)(z1B + NH);
    float*  f_pl2 = f_pl + (size_t)GNUM * HDIM;
    float*  b_fold = f_pl2 + (size_t)GNUM * HDIM;          // 3*128 f32

    ushort* Wt_in   = (ushort*)(b_fold + 3 * HDIM);        // 6*128*128
    ushort* Wt_n2   = Wt_in + (size_t)6 * HDIM * HDIM;     // 3*128*128
    ushort* Wt_fold = Wt_n2 + (size_t)3 * HDIM * HDIM;     // 3*128*256

    int*  cnt0 = (int*)(Wt_fold + (size_t)3 * HDIM * 2 * HDIM);
    int*  cnt1 = cnt0 + NNODES;
    uint* bk0  = (uint*)(cnt1 + NNODES);
    uint* bk1  = bk0 + ((size_t)NNODES << 6);

    const int gemm_grid = (NNODES + 63) / 64;
    const int edge_grid = (NEDGES + 255) / 256;
    const dim3 node_grid((NNODES + 3) / 4, 2);

    wtrans_all<<<9, 512, 0, stream>>>(W_in, Wn2, Wt_in, Wt_n2);
    wfold<<<dim3(64, 3), 256, 0, stream>>>(W_out, b_out, Wn1, bn1, Wt_fold, b_fold);
    hipMemsetAsync(cnt0, 0, 2 * NNODES * sizeof(int), stream);
    fill2<<<dim3(edge_grid, 2), 256, 0, stream>>>(ei, ew, cnt0, cnt1, bk0, bk1);

    int ci = -1;   // -1: cur = x (f32)
    for (int l = 0; l < LNUM; ++l) {
        const int t0 = (l == 0) ? 0 : (ci + 1) % 3;
        const int t1 = (l == 0) ? 1 : (ci + 2) % 3;
        const void* curp = (l == 0) ? (const void*)x : (const void*)nb[ci];
        const int a_bf = (l == 0) ? 0 : 1;
        const int lo0 = l * ONUM, lo1 = lo0 + 1;

        // z_o = cur @ W_in[lo] + b_in -> bf16 z ; hid_o = fW[0]*z_o (bf16). Both orders.
        mfma_gemm<<<dim3(gemm_grid, 2), 256, 0, stream>>>(
            curp, a_bf, Wt_in + (size_t)lo0 * HDIM * HDIM,
            b_in + (size_t)lo0 * HDIM, fW + (size_t)lo0 * (KHOPS + 1), z0A, nb[t0],
            Wt_in + (size_t)lo1 * HDIM * HDIM, b_in + (size_t)lo1 * HDIM,
            fW + (size_t)lo1 * (KHOPS + 1), z1A, nb[t1]);

        ushort *pa0 = z0A, *pb0 = z0B, *pa1 = z1A, *pb1 = z1B;
        for (int k = 1; k <= KHOPS; ++k) {
            spmm2<<<node_grid, 256, 0, stream>>>(
                cnt0, bk0, cnt1, bk1, pa0, pb0, pa1, pb1, nb[t0], nb[t1],
                fW + (size_t)lo0 * (KHOPS + 1) + (k - 1),
                fW + (size_t)lo1 * (KHOPS + 1) + (k - 1),
                (k & 1) == 0, k < KHOPS);
            ushort* t;
            t = pa0; pa0 = pb0; pb0 = t;
            t = pa1; pa1 = pb1; pb1 = t;
        }
        // h = relu(bn2( relu(bn1([hid0|hid1]@Wfold+bfold)) @ Wn2 + bn2 )) -> nb[t0]
        mfma_gemm2<<<gemm_grid, 256, 0, stream>>>(
            nb[t0], nb[t1],
            Wt_fold + (size_t)l * HDIM * 2 * HDIM, b_fold + (size_t)l * HDIM,
            g1 + (size_t)l * HDIM, be1 + (size_t)l * HDIM,
            Wt_n2 + (size_t)l * HDIM * HDIM, bn2 + (size_t)l * HDIM,
            g2 + (size_t)l * HDIM, be2 + (size_t)l * HDIM,
            nb[t0]);
        ci = t0;
    }

    pool_seg<<<GNUM, 1024, 0, stream>>>(nb[ci], batch, f_pl);
    gemm_rows<<<(GNUM + 7) / 8, 128, 0, stream>>>(f_pl,  W1, b1, f_pl2, GNUM, HDIM, 1);
    gemm_rows<<<(GNUM + 7) / 8, 128, 0, stream>>>(f_pl2, W2, b2, out,   GNUM, CDIM, 0);
}